// Round 15
// baseline (189.282 us; speedup 1.0000x reference)
//
#include <hip/hip_runtime.h>

// GPT2 attention w/ soft-threshold pruning — round 15.
// vs r14 (failed absmax 0.0354): r14's two score-error adders were the Wq-split
// drop (+3.7e-3) and __fdividef on the C+(s-C)*sig form (+2.4e-3 abs on a ~1e4
// quotient); they add LINEARLY with K-rounding (same amplified entries).
// Fix: (1) restore Wq-side split (Q = split x split, 3 MFMA). (2) soft-threshold
// reformulated as w = s - (s-C)*E/(1+E), E=e^{-10s}, for s > -1.5 (quotient
// <= ~90 -> fdividef abs err ~2e-5, BETTER than IEEE on the old form); for
// s <= -1.5 numpy's f32 C+x rounds to exactly C, so w = C exact-match.
// Keep defer-max (exact) + fdividef in non-amplified normalize/merge.

#define S_LEN 2048
#define DM    1024
#define NH    16
#define HD    64
#define SLOPE 10.0f
#define CMASK -10000.0f
#define SP    2080      // padded V^T row stride (shorts)

typedef short s16x4 __attribute__((ext_vector_type(4)));
typedef short s16x8 __attribute__((ext_vector_type(8)));
typedef float f32x4 __attribute__((ext_vector_type(4)));

#define MFMA16(a,b,c) __builtin_amdgcn_mfma_f32_16x16x32_bf16(a,b,c,0,0,0)
#define GLDS16(g,l) __builtin_amdgcn_global_load_lds( \
    (const __attribute__((address_space(1))) void*)(g), \
    (__attribute__((address_space(3))) void*)(l), 16, 0, 0)

__device__ __forceinline__ short f2bf(float f){
    unsigned u = __float_as_uint(f);
    u += 0x7fffu + ((u >> 16) & 1u);          // RNE
    return (short)(u >> 16);
}
__device__ __forceinline__ float bf2f(short x){
    return __uint_as_float(((unsigned)(unsigned short)x) << 16);
}
struct bfpair { short hi, lo; };
__device__ __forceinline__ bfpair split_bf(float x){
    bfpair r; r.hi = f2bf(x);
    r.lo = f2bf(x - bf2f(r.hi));
    return r;
}

// soft-threshold: w' = C + (s-C)*sigmoid(10s), computed in the cancellation-
// free form s - (s-C)*E/(1+E). For s <= -1.5, sigma(10s) < 5e-8 and numpy's
// f32 C + (s-C)*sigma rounds to exactly C -> return C (bit-match). E=inf for
// s < -8.8 makes the dead select arm NaN, which cndmask discards.
__device__ __forceinline__ float softthr(float sv){
    float E = __expf(-SLOPE*sv);
    float w = sv - __fdividef((sv - CMASK)*E, 1.f + E);
    return (sv > -1.5f) ? w : CMASK;
}

// ---- staging: [ROWS][64] bf16 tile via global_load_lds, XOR-swizzled ----
template<int ROWS, int THREADS>
__device__ __forceinline__ void stage_tile(const short* gbase, int rstride,
                                           short* lds, int tid){
#pragma unroll
    for (int it = 0; it < ROWS*8/THREADS; ++it){
        int s = it*THREADS + tid;
        int row = s >> 3, grp = s & 7;
        const short* src = gbase + (size_t)row*rstride + ((grp ^ (row & 7)) << 3);
        GLDS16(src, lds + (size_t)s*8);
    }
}
__device__ __forceinline__ s16x8 frag(const short* lds, int row, int kg){
    return *(const s16x8*)&lds[row*64 + ((kg ^ (row & 7)) << 3)];
}

// ---------- QKV GEMM, single dispatch: grid (24,16), 128x128 tiles ----------
// sec = bcol>>10: 0 = Q (split x split, 3 MFMA, split head-major out),
// 1 = K (plain, bf16 head-major out), 2 = V (plain, bf16 [s][1024] out).
__global__ __launch_bounds__(256)
void gemm_qkv(const short* __restrict__ Ahg, const short* __restrict__ Alg,
              const short* __restrict__ Bhg, const short* __restrict__ Blg,
              const float* __restrict__ bias,
              short* __restrict__ QHh, short* __restrict__ QHl,
              short* __restrict__ KH,  short* __restrict__ Vb)
{
    __shared__ __align__(16) short Ah_s[128*64];
    __shared__ __align__(16) short Bh_s[128*64];
    __shared__ __align__(16) short Al_s[128*64];
    __shared__ __align__(16) short Bl_s[128*64];

    const int tid = threadIdx.x, lane = tid & 63, wid = tid >> 6;
    const int lr = lane & 15, lg = lane >> 4;
    const int brow = blockIdx.y*128, bcol = blockIdx.x*128;
    const int sec = bcol >> 10;
    const int wm = (wid >> 1)*64, wn = (wid & 1)*64;

    f32x4 acc[4][4];
#pragma unroll
    for (int m = 0; m < 4; ++m)
#pragma unroll
        for (int n = 0; n < 4; ++n) acc[m][n] = (f32x4){0.f,0.f,0.f,0.f};

    for (int k0 = 0; k0 < DM; k0 += 64){
        stage_tile<128,256>(Ahg + (size_t)brow*DM + k0, DM, Ah_s, tid);
        stage_tile<128,256>(Bhg + (size_t)bcol*DM + k0, DM, Bh_s, tid);
        if (sec == 0){
            stage_tile<128,256>(Alg + (size_t)brow*DM + k0, DM, Al_s, tid);
            stage_tile<128,256>(Blg + (size_t)bcol*DM + k0, DM, Bl_s, tid);
        }
        __syncthreads();
#pragma unroll
        for (int kc = 0; kc < 2; ++kc){
            s16x8 ah[4], al[4], bh[4], bl[4];
#pragma unroll
            for (int m = 0; m < 4; ++m)
                ah[m] = frag(Ah_s, wm + m*16 + lr, kc*4 + lg);
#pragma unroll
            for (int n = 0; n < 4; ++n)
                bh[n] = frag(Bh_s, wn + n*16 + lr, kc*4 + lg);
            if (sec == 0){
#pragma unroll
                for (int m = 0; m < 4; ++m)
                    al[m] = frag(Al_s, wm + m*16 + lr, kc*4 + lg);
#pragma unroll
                for (int n = 0; n < 4; ++n)
                    bl[n] = frag(Bl_s, wn + n*16 + lr, kc*4 + lg);
            }
#pragma unroll
            for (int m = 0; m < 4; ++m)
#pragma unroll
                for (int n = 0; n < 4; ++n){
                    acc[m][n] = MFMA16(ah[m], bh[n], acc[m][n]);
                    if (sec == 0){
                        acc[m][n] = MFMA16(ah[m], bl[n], acc[m][n]);
                        acc[m][n] = MFMA16(al[m], bh[n], acc[m][n]);
                    }
                }
        }
        __syncthreads();
    }

#pragma unroll
    for (int m = 0; m < 4; ++m)
#pragma unroll
        for (int n = 0; n < 4; ++n){
            int row  = brow + wm + m*16 + lg*4;
            int gcol = bcol + wn + n*16 + lr;
            float bv = bias[gcol];
            int h0 = (gcol & 1023) >> 6, d = gcol & 63;
#pragma unroll
            for (int v = 0; v < 4; ++v){
                float val = acc[m][n][v] + bv;
                if (sec == 0){
                    bfpair p = split_bf(val);
                    size_t o = ((size_t)h0*S_LEN + row + v)*HD + d;
                    QHh[o] = p.hi; QHl[o] = p.lo;
                } else if (sec == 1){
                    KH[((size_t)h0*S_LEN + row + v)*HD + d] = f2bf(val);
                } else {
                    Vb[(size_t)(row + v)*DM + (gcol & 1023)] = f2bf(val);
                }
            }
        }
}

// ---------------- proj GEMM: C = A@W^T + bias, f32 out ----------------
__global__ __launch_bounds__(256)
void gemm_proj(const short* __restrict__ Ahg, const short* __restrict__ Bhg,
               const float* __restrict__ bias, float* __restrict__ C)
{
    __shared__ __align__(16) short Ah_s[128*64];
    __shared__ __align__(16) short Bh_s[128*64];

    const int tid = threadIdx.x, lane = tid & 63, wid = tid >> 6;
    const int lr = lane & 15, lg = lane >> 4;
    const int brow = blockIdx.y*128, bcol = blockIdx.x*128;
    const int wm = (wid >> 1)*64, wn = (wid & 1)*64;

    f32x4 acc[4][4];
#pragma unroll
    for (int m = 0; m < 4; ++m)
#pragma unroll
        for (int n = 0; n < 4; ++n) acc[m][n] = (f32x4){0.f,0.f,0.f,0.f};

    for (int k0 = 0; k0 < DM; k0 += 64){
        stage_tile<128,256>(Ahg + (size_t)brow*DM + k0, DM, Ah_s, tid);
        stage_tile<128,256>(Bhg + (size_t)bcol*DM + k0, DM, Bh_s, tid);
        __syncthreads();
#pragma unroll
        for (int kc = 0; kc < 2; ++kc){
            s16x8 ah[4], bh[4];
#pragma unroll
            for (int m = 0; m < 4; ++m)
                ah[m] = frag(Ah_s, wm + m*16 + lr, kc*4 + lg);
#pragma unroll
            for (int n = 0; n < 4; ++n)
                bh[n] = frag(Bh_s, wn + n*16 + lr, kc*4 + lg);
#pragma unroll
            for (int m = 0; m < 4; ++m)
#pragma unroll
                for (int n = 0; n < 4; ++n)
                    acc[m][n] = MFMA16(ah[m], bh[n], acc[m][n]);
        }
        __syncthreads();
    }

#pragma unroll
    for (int m = 0; m < 4; ++m)
#pragma unroll
        for (int n = 0; n < 4; ++n){
            int row  = brow + wm + m*16 + lg*4;
            int gcol = bcol + wn + n*16 + lr;
            float bv = bias[gcol];
#pragma unroll
            for (int v = 0; v < 4; ++v)
                C[(size_t)(row + v)*DM + gcol] = acc[m][n][v] + bv;
        }
}

// ---------------- prep kernels ----------------
__global__ __launch_bounds__(256)
void split_f32(const float* __restrict__ x, short* __restrict__ h,
               short* __restrict__ l, int n4)
{
    int i = blockIdx.x*256 + threadIdx.x;
    if (i >= n4) return;
    float4 v = *(const float4*)&x[(size_t)i*4];
    bfpair a = split_bf(v.x), b = split_bf(v.y), c = split_bf(v.z), d = split_bf(v.w);
    s16x4 hv, lv;
    hv.x = a.hi; hv.y = b.hi; hv.z = c.hi; hv.w = d.hi;
    lv.x = a.lo; lv.y = b.lo; lv.z = c.lo; lv.w = d.lo;
    *(s16x4*)&h[(size_t)i*4] = hv;
    *(s16x4*)&l[(size_t)i*4] = lv;
}

// W [1024][N] f32 -> W^T [N][1024] bf16 hi; lo only for first 1024 cols if SPL
template<bool SPL>
__global__ __launch_bounds__(256)
void wtrans(const float* __restrict__ W, int N, short* __restrict__ Th,
            short* __restrict__ Tl)
{
    __shared__ float t[64][65];
    const int tid = threadIdx.x;
    const int tn = blockIdx.x*64, tk = blockIdx.y*64;
#pragma unroll
    for (int it = 0; it < 4; ++it){
        int idx = tid + it*256;
        int r = idx >> 4, c4 = (idx & 15)*4;
        float4 v = *(const float4*)&W[(size_t)(tk + r)*N + tn + c4];
        t[r][c4] = v.x; t[r][c4+1] = v.y; t[r][c4+2] = v.z; t[r][c4+3] = v.w;
    }
    __syncthreads();
#pragma unroll
    for (int it = 0; it < 4; ++it){
        int idx = tid + it*256;
        int n = idx >> 4, c4 = (idx & 15)*4;
        s16x4 hv, lv;
#pragma unroll
        for (int j = 0; j < 4; ++j){
            bfpair p = split_bf(t[c4+j][n]);
            hv[j] = p.hi; lv[j] = p.lo;
        }
        *(s16x4*)&Th[(size_t)(tn + n)*DM + tk + c4] = hv;
        if (SPL && tn < DM)
            *(s16x4*)&Tl[(size_t)(tn + n)*DM + tk + c4] = lv;
    }
}

// V [2048][1024] bf16 -> V^T [1024][SP] bf16 (padded stride)
__global__ __launch_bounds__(256)
void vtrans(const short* __restrict__ Vb, short* __restrict__ Vt)
{
    __shared__ short t[64][66];
    const int tid = threadIdx.x;
    const int td = blockIdx.x*64, ts = blockIdx.y*64;
#pragma unroll
    for (int it = 0; it < 4; ++it){
        int idx = tid + it*256;
        int r = idx >> 4, c4 = (idx & 15)*4;
        s16x4 v = *(const s16x4*)&Vb[(size_t)(ts + r)*DM + td + c4];
        t[r][c4] = v.x; t[r][c4+1] = v.y; t[r][c4+2] = v.z; t[r][c4+3] = v.w;
    }
    __syncthreads();
#pragma unroll
    for (int it = 0; it < 4; ++it){
        int idx = tid + it*256;
        int n = idx >> 4, c4 = (idx & 15)*4;
        s16x4 o;
#pragma unroll
        for (int j = 0; j < 4; ++j) o[j] = t[c4+j][n];
        *(s16x4*)&Vt[(size_t)(td + n)*SP + ts + c4] = o;
    }
}

// per-64-key-block partial sums of V, then per-head suffix sums
__global__ __launch_bounds__(64)
void sv_partial(const short* __restrict__ Vb, float* __restrict__ PB)
{
    int b = blockIdx.x, h = blockIdx.y, d = threadIdx.x;
    float s = 0.f;
#pragma unroll 8
    for (int k = 0; k < 64; ++k)
        s += bf2f(Vb[(size_t)(b*64 + k)*DM + h*HD + d]);
    PB[((size_t)h*32 + b)*64 + d] = s;
}
__global__ __launch_bounds__(64)
void sv_suffix(const float* __restrict__ PB, float* __restrict__ SSV)
{
    int h = blockIdx.x, d = threadIdx.x;
    float s = 0.f;
    SSV[((size_t)h*33 + 32)*64 + d] = 0.f;
    for (int b = 31; b >= 0; --b){
        s += PB[((size_t)h*32 + b)*64 + d];
        SSV[((size_t)h*33 + b)*64 + d] = s;
    }
}

// -------- attn: 1280 blocks x 4 waves; block = (h, 64-row q-tile, <=8 kvb) --
__global__ __launch_bounds__(256)
void attn_fwd(const short* __restrict__ QHh, const short* __restrict__ QHl,
              const short* __restrict__ KH, const short* __restrict__ Vt,
              short* __restrict__ acc0, short* __restrict__ acc1,
              short* __restrict__ acc2, float* __restrict__ ML)
{
    __shared__ __align__(16) short kh_s[64*64];
    __shared__ __align__(16) short vt_s[64*64];
    __shared__ __align__(16) short Ps[4][16*72];

    const int j = blockIdx.x;                      // 0..1279
    const int h = (j & 7) + 8*((j >> 3) & 1);      // == j&15; XCD-pinned heads
    const int t = j >> 4;                          // 0..79
    int qst, c;
    if (t < 8)      { qst = t; c = 0; }
    else if (t < 24){ int u = t - 8;  qst = 8  + (u >> 1); c = u & 1; }
    else if (t < 48){ int u = t - 24; qst = 16 + u/3;      c = u - (u/3)*3; }
    else            { int u = t - 48; qst = 24 + (u >> 2); c = u & 3; }
    const int kv0 = c*8;
    const int kv1 = min(kv0 + 8, qst + 1);

    const int tid = threadIdx.x, lane = tid & 63, wid = tid >> 6;
    const int lr = lane & 15, lg = lane >> 4;
    const int qrow = qst*64 + wid*16 + lg*4;

    const short* qbh = QHh + ((size_t)h*S_LEN + qst*64 + wid*16)*HD;
    const short* qbl = QHl + ((size_t)h*S_LEN + qst*64 + wid*16)*HD;
    s16x8 aqh[2], aql[2];
#pragma unroll
    for (int kc = 0; kc < 2; ++kc){
        aqh[kc] = *(const s16x8*)&qbh[lr*HD + kc*32 + lg*8];
        aql[kc] = *(const s16x8*)&qbl[lr*HD + kc*32 + lg*8];
    }

    float m_run[4], l_run[4];
    f32x4 acc_o[4];
#pragma unroll
    for (int v = 0; v < 4; ++v){ m_run[v] = -1e30f; l_run[v] = 0.f; }
#pragma unroll
    for (int n = 0; n < 4; ++n) acc_o[n] = (f32x4){0.f,0.f,0.f,0.f};

    for (int kvb = kv0; kvb < kv1; ++kvb){
        __syncthreads();
        stage_tile<64,256>(KH + ((size_t)h*S_LEN + kvb*64)*HD, HD, kh_s, tid);
        stage_tile<64,256>(Vt + (size_t)(h*HD)*SP + kvb*64, SP, vt_s, tid);
        __syncthreads();

        // S = Q K^T (Q split hi/lo, K plain)
        f32x4 sc[4];
#pragma unroll
        for (int n = 0; n < 4; ++n) sc[n] = (f32x4){0.f,0.f,0.f,0.f};
#pragma unroll
        for (int kc = 0; kc < 2; ++kc)
#pragma unroll
            for (int n = 0; n < 4; ++n){
                s16x8 bkh = frag(kh_s, n*16 + lr, kc*4 + lg);
                sc[n] = MFMA16(aqh[kc], bkh, sc[n]);
                sc[n] = MFMA16(aql[kc], bkh, sc[n]);
            }

        // soft-threshold (+ causal mask only in diagonal block kvb==qst)
        float p[4][4], tmax[4];
#pragma unroll
        for (int v = 0; v < 4; ++v) tmax[v] = -1e30f;
        if (kvb == qst){
#pragma unroll
            for (int n = 0; n < 4; ++n){
                int key = kvb*64 + n*16 + lr;
#pragma unroll
                for (int v = 0; v < 4; ++v){
                    float w = (key > qrow + v) ? CMASK : softthr(sc[n][v]);
                    p[n][v] = w;
                    tmax[v] = fmaxf(tmax[v], w);
                }
            }
        } else {
#pragma unroll
            for (int n = 0; n < 4; ++n)
#pragma unroll
                for (int v = 0; v < 4; ++v){
                    float w = softthr(sc[n][v]);
                    p[n][v] = w;
                    tmax[v] = fmaxf(tmax[v], w);
                }
        }
#pragma unroll
        for (int v = 0; v < 4; ++v)
#pragma unroll
            for (int msk = 1; msk < 16; msk <<= 1)
                tmax[v] = fmaxf(tmax[v], __shfl_xor(tmax[v], msk, 64));

        // defer-max: rescale only when the block max actually grows (exact:
        // when it doesn't, scale == exp(0) == 1 and skipping is identity).
        int up = 0;
#pragma unroll
        for (int v = 0; v < 4; ++v) up |= (tmax[v] > m_run[v]);
        const bool grow = __any(up);

        float scale[4];
        if (grow){
#pragma unroll
            for (int v = 0; v < 4; ++v){
                float mn = fmaxf(m_run[v], tmax[v]);
                scale[v] = __expf(m_run[v] - mn);
                m_run[v] = mn;
            }
        }

        float rsum[4];
#pragma unroll
        for (int v = 0; v < 4; ++v) rsum[v] = 0.f;
#pragma unroll
        for (int n = 0; n < 4; ++n)
#pragma unroll
            for (int v = 0; v < 4; ++v){
                float e = __expf(p[n][v] - m_run[v]);
                p[n][v] = e;
                rsum[v] += e;
            }
#pragma unroll
        for (int v = 0; v < 4; ++v)
#pragma unroll
            for (int msk = 1; msk < 16; msk <<= 1)
                rsum[v] += __shfl_xor(rsum[v], msk, 64);

        if (grow){
#pragma unroll
            for (int v = 0; v < 4; ++v) l_run[v] = l_run[v]*scale[v] + rsum[v];
#pragma unroll
            for (int n = 0; n < 4; ++n)
#pragma unroll
                for (int v = 0; v < 4; ++v) acc_o[n][v] *= scale[v];
        } else {
#pragma unroll
            for (int v = 0; v < 4; ++v) l_run[v] += rsum[v];
        }

        // P (D-layout) -> per-wave LDS -> A-frag layout
#pragma unroll
        for (int n = 0; n < 4; ++n)
#pragma unroll
            for (int v = 0; v < 4; ++v)
                Ps[wid][(lg*4 + v)*72 + 16*n + lr] = f2bf(p[n][v]);
        asm volatile("s_waitcnt lgkmcnt(0)" ::: "memory");

        s16x8 pa0 = *(const s16x8*)&Ps[wid][lr*72 + lg*8];
        s16x8 pa1 = *(const s16x8*)&Ps[wid][lr*72 + 32 + lg*8];
#pragma unroll
        for (int n = 0; n < 4; ++n){
            s16x8 bv0 = frag(vt_s, 16*n + lr, lg);      // keys 0..31
            s16x8 bv1 = frag(vt_s, 16*n + lr, 4 + lg);  // keys 32..63
            acc_o[n] = MFMA16(pa0, bv0, acc_o[n]);
            acc_o[n] = MFMA16(pa1, bv1, acc_o[n]);
        }
    }

    // store partial: 64 rows x 64 d bf16 + (m,l) f32 per row
    short* ab = (j < 512) ? acc0 + (size_t)j*4096
              : (j < 768) ? acc1 + (size_t)(j-512)*4096
                          : acc2 + (size_t)(j-768)*4096;
#pragma unroll
    for (int n = 0; n < 4; ++n)
#pragma unroll
        for (int v = 0; v < 4; ++v)
            ab[(wid*16 + lg*4 + v)*64 + 16*n + lr] = f2bf(acc_o[n][v]);
    if (lr == 0){
#pragma unroll
        for (int v = 0; v < 4; ++v){
            ML[((size_t)j*64 + wid*16 + lg*4 + v)*2 + 0] = m_run[v];
            ML[((size_t)j*64 + wid*16 + lg*4 + v)*2 + 1] = l_run[v];
        }
    }
}

// ---------------- merge partials + analytic tail -> O bf16 [s][1024] --------
__global__ __launch_bounds__(256)
void attn_merge(const short* __restrict__ acc0, const short* __restrict__ acc1,
                const short* __restrict__ acc2, const float* __restrict__ ML,
                const float* __restrict__ SSV, short* __restrict__ O)
{
    const int b = blockIdx.x;          // 0..511
    const int h = b & 15, qst = b >> 4;
    const int d = threadIdx.x & 63, rg = threadIdx.x >> 6;
    const int C = (qst + 8) >> 3;
    const int tbase = (qst < 8)  ? qst
                    : (qst < 16) ? 8  + 2*(qst - 8)
                    : (qst < 24) ? 24 + 3*(qst - 16)
                                 : 48 + 4*(qst - 24);
    const float F = (float)(S_LEN - 64*(qst + 1));
    const float svd = SSV[((size_t)h*33 + (qst + 1))*64 + d];

    for (int i = 0; i < 16; ++i){
        int r = rg + 4*i;              // 0..63
        float M = -1e30f;
        for (int c = 0; c < C; ++c){
            int job = (tbase + c)*16 + h;
            M = fmaxf(M, ML[((size_t)job*64 + r)*2]);
        }
        float num = 0.f, den = 0.f;
        for (int c = 0; c < C; ++c){
            int job = (tbase + c)*16 + h;
            float m = ML[((size_t)job*64 + r)*2];
            float l = ML[((size_t)job*64 + r)*2 + 1];
            const short* ab = (job < 512) ? acc0 + (size_t)job*4096
                            : (job < 768) ? acc1 + (size_t)(job-512)*4096
                                          : acc2 + (size_t)(job-768)*4096;
            float e = __expf(m - M);
            num += e * bf2f(ab[r*64 + d]);
            den += e * l;
        }
        float et = __expf(CMASK - M);
        num += et * svd;
        den += et * F;
        O[(size_t)(qst*64 + r)*DM + h*64 + d] = f2bf(num * __fdividef(1.f, den));
    }
}

extern "C" void kernel_launch(void* const* d_in, const int* in_sizes, int n_in,
                              void* d_out, int out_size, void* d_ws, size_t ws_size,
                              hipStream_t stream)
{
    (void)in_sizes; (void)n_in; (void)out_size; (void)ws_size;
    const float* hs   = (const float*)d_in[0];
    const float* wqkv = (const float*)d_in[1];
    const float* bqkv = (const float*)d_in[2];
    const float* wprj = (const float*)d_in[3];
    const float* bprj = (const float*)d_in[4];

    char* p = (char*)d_ws;                        // ~39.7 MiB used
    short* Ahg  = (short*)(p + (0ull  << 20));    // 4 MiB  (-> O after attn)
    short* Alg  = (short*)(p + (4ull  << 20));    // 4 MiB  (-> acc seg0: jobs 0..511)
    short* WqTh = (short*)(p + (8ull  << 20));    // 6 MiB  (-> WpT)
    short* WqTl = (short*)(p + (14ull << 20));    // 2 MiB  (-> acc seg1: jobs 512..767)
    short* QHh  = (short*)(p + (16ull << 20));    // 4 MiB (head-major)
    short* QHl  = (short*)(p + (20ull << 20));    // 4 MiB
    short* KH   = (short*)(p + (24ull << 20));    // 4 MiB (head-major)
    short* Vbg  = (short*)(p + (28ull << 20));    // 4 MiB (-> acc seg2: jobs 768..1279)
    short* VT   = (short*)(p + (32ull << 20));    // 4.07 MiB, ends ~36.06 MiB
    float* PB   = (float*)(p + (38ull << 20));                     // 128 KiB
    float* SSV  = (float*)(p + (38ull << 20) + (256ull << 10));    // 132 KiB
    float* ML   = (float*)(p + (39ull << 20));                     // 640 KiB
    short* O    = Ahg;
    short* WpT  = WqTh;

    split_f32<<<S_LEN*DM/4/256, 256, 0, stream>>>(hs, Ahg, Alg, S_LEN*DM/4);
    wtrans<true><<<dim3(3*DM/64, DM/64), 256, 0, stream>>>(wqkv, 3*DM, WqTh, WqTl);

    gemm_qkv<<<dim3(24, 16), 256, 0, stream>>>(
        Ahg, Alg, WqTh, WqTl, bqkv, QHh, QHl, KH, Vbg);

    wtrans<false><<<dim3(DM/64, DM/64), 256, 0, stream>>>(wprj, DM, WpT, nullptr);
    vtrans<<<dim3(DM/64, S_LEN/64), 256, 0, stream>>>(Vbg, VT);
    sv_partial<<<dim3(32, NH), 64, 0, stream>>>(Vbg, PB);
    sv_suffix<<<NH, 64, 0, stream>>>(PB, SSV);

    attn_fwd<<<1280, 256, 0, stream>>>(QHh, QHl, KH, VT, Alg, WqTl, Vbg, ML);
    attn_merge<<<512, 256, 0, stream>>>(Alg, WqTl, Vbg, ML, SSV, O);

    gemm_proj<<<dim3(8, 16), 256, 0, stream>>>(O, WpT, bprj, (float*)d_out);
}